// Round 18
// baseline (144.074 us; speedup 1.0000x reference)
//
#include <hip/hip_runtime.h>
#include <hip/hip_bf16.h>

#define T_LEN 800
#define B_SZ  16
#define D_IN  80
#define CCH   256
#define OUT_CH 222
#define HOPSZ 256
#define WINSZ 512
#define ZLEN  (T_LEN*HOPSZ)   // 204800
#define CSTRIDE 256           // ccep row stride ([t][co] layout)
#define XSTR 104              // bf16 row stride for staged x

#define PHI(i) ((i) + ((i)>>3))

typedef short short8 __attribute__((ext_vector_type(8)));
typedef float f32x4 __attribute__((ext_vector_type(4)));

__device__ __forceinline__ float2 cmul(float2 a, float2 b){
    return make_float2(a.x*b.x - a.y*b.y, a.x*b.y + a.y*b.x);
}

// -------- weight transforms --------
// w2t/w3t: float4 [ci][co].  w1f: conv1 fragment-split, k=ci (pad 80->96),
// idx = (((d*3+kt)*4+lg)*256+co)*8+e with ci = kt*32+lg*8+e.  wf4: conv4 table.
__global__ __launch_bounds__(256) void k_wtrans(const float* __restrict__ W1,
                                                const float* __restrict__ W2,
                                                const float* __restrict__ W3,
                                                const float* __restrict__ W4,
                                                float4* __restrict__ w2t,
                                                float4* __restrict__ w3t,
                                                __hip_bfloat16* __restrict__ w1fhi,
                                                __hip_bfloat16* __restrict__ w1flo,
                                                __hip_bfloat16* __restrict__ wfhi,
                                                __hip_bfloat16* __restrict__ wflo){
    const int i = blockIdx.x*256 + threadIdx.x;
    switch (blockIdx.y){
    case 0: if (i < 32*256){
        int cil = i >> 8, co = i & 255;
        const float* s = &W2[(co*32 + cil)*3];
        w2t[i] = make_float4(s[0], s[1], s[2], 0.f);
    } break;
    case 1: if (i < 32*256){
        int cil = i >> 8, co = i & 255;
        const float* s = &W3[(co*32 + cil)*3];
        w3t[i] = make_float4(s[0], s[1], s[2], 0.f);
    } break;
    case 2: if (i < 9*4*256*8){
        int e  = i & 7;
        int co = (i >> 3) & 255;
        int lg = (i >> 11) & 3;
        int dk = i >> 13;            // 0..8
        int d  = dk / 3, kt = dk - 3*d;
        int ci = kt*32 + lg*8 + e;
        float w = (ci < 80) ? W1[(co*80 + ci)*3 + d] : 0.f;
        __hip_bfloat16 h = __float2bfloat16(w);
        __hip_bfloat16 l = __float2bfloat16(w - __bfloat162float(h));
        w1fhi[i] = h;
        w1flo[i] = l;
    } break;
    default: if (i < 768*256){
        int k = i >> 8, co = i & 255;
        int d = k >> 8, ci = k & 255;
        float w = 0.f;
        if (co < OUT_CH){
            float q = (co < 111) ? (float)(111 - co) : (float)(co - 110);
            w = W4[(co*256 + ci)*3 + d] / q;   // fold 1/quef into weights
        }
        __hip_bfloat16 h = __float2bfloat16(w);
        __hip_bfloat16 l = __float2bfloat16(w - __bfloat162float(h));
        int kt = k >> 5, g = (k >> 3) & 3, e = k & 7;
        int idx = ((kt*4 + g)*256 + co)*8 + e;
        wfhi[idx] = h;
        wflo[idx] = l;
    } break;
    }
}

// -------- fused conv1(MFMA)+conv2+conv3: x -> bf16 hi/lo planes --------
__global__ __launch_bounds__(256) void k_conv123(const float* __restrict__ x,
                                                 const __hip_bfloat16* __restrict__ w1fhi,
                                                 const __hip_bfloat16* __restrict__ w1flo,
                                                 const float* __restrict__ b1,
                                                 const float4* __restrict__ W2t,
                                                 const float* __restrict__ b2,
                                                 const float4* __restrict__ W3t,
                                                 const float* __restrict__ b3,
                                                 __hip_bfloat16* __restrict__ ohi,
                                                 __hip_bfloat16* __restrict__ olo){
    __shared__ __align__(16) __hip_bfloat16 xhi[34*XSTR];  // x rows t0-3..t0+30
    __shared__ __align__(16) __hip_bfloat16 xlo[34*XSTR];
    __shared__ __align__(16) float hs[256*20];             // [co][t-local]
    const int t0 = blockIdx.x * 16;
    const int b  = blockIdx.y;
    const int tid = threadIdx.x;
    const int co = tid;
    const int gbase = (co >> 5) << 5;
    const int wave = tid >> 6;
    const int l = tid & 63;
    const int l15 = l & 15, lg4 = l >> 4;

    // stage x as split bf16; pad columns [80,104) zeroed
    for (int i = tid; i < 34*XSTR; i += 256){
        int rr = i / XSTR, c = i - rr*XSTR;
        float v = 0.f;
        if (c < 80){
            int t = t0 - 3 + rr;
            v = (t >= 0 && t < T_LEN) ? x[(b*T_LEN + t)*D_IN + c] : 0.f;
        }
        __hip_bfloat16 h = __float2bfloat16(v);
        xhi[i] = h;
        xlo[i] = __float2bfloat16(v - __bfloat162float(h));
    }
    __syncthreads();

    // conv1 via MFMA: trow = local output row (t = t0-2+trow), staged row = trow + d
    {
        f32x4 acc1[2][4];
        #pragma unroll
        for (int n = 0; n < 4; ++n){
            float bv = b1[(wave << 6) + (n << 4) + l15];
            acc1[0][n] = f32x4{bv, bv, bv, bv};
            acc1[1][n] = f32x4{bv, bv, bv, bv};
        }
        #pragma unroll
        for (int d = 0; d < 3; ++d){
            #pragma unroll
            for (int kt = 0; kt < 3; ++kt){
                short8 ah[2], al[2];
                #pragma unroll
                for (int m = 0; m < 2; ++m){
                    int off = ((m << 4) + l15 + d)*XSTR + kt*32 + lg4*8;
                    ah[m] = __builtin_bit_cast(short8, *(const uint4*)(xhi + off));
                    al[m] = __builtin_bit_cast(short8, *(const uint4*)(xlo + off));
                }
                #pragma unroll
                for (int n = 0; n < 4; ++n){
                    int co_n = (wave << 6) + (n << 4) + l15;
                    int wo = ((((d*3 + kt)*4 + lg4) << 8) + co_n) << 3;
                    short8 bh = __builtin_bit_cast(short8, *(const uint4*)(w1fhi + wo));
                    short8 bl = __builtin_bit_cast(short8, *(const uint4*)(w1flo + wo));
                    #pragma unroll
                    for (int m = 0; m < 2; ++m){
                        acc1[m][n] = __builtin_amdgcn_mfma_f32_16x16x32_bf16(ah[m], bh, acc1[m][n], 0, 0, 0);
                        acc1[m][n] = __builtin_amdgcn_mfma_f32_16x16x32_bf16(ah[m], bl, acc1[m][n], 0, 0, 0);
                        acc1[m][n] = __builtin_amdgcn_mfma_f32_16x16x32_bf16(al[m], bh, acc1[m][n], 0, 0, 0);
                    }
                }
            }
        }
        // writeback: relu + zero-mask outside [0,T); hs[co][trow], trow<20
        #pragma unroll
        for (int m = 0; m < 2; ++m){
            #pragma unroll
            for (int n = 0; n < 4; ++n){
                int co_n = (wave << 6) + (n << 4) + l15;
                #pragma unroll
                for (int j = 0; j < 4; ++j){
                    int trow = (m << 4) + (lg4 << 2) + j;
                    if (trow < 20){
                        int t = t0 - 2 + trow;
                        float v = (t >= 0 && t < T_LEN) ? fmaxf(acc1[m][n][j], 0.f) : 0.f;
                        hs[co_n*20 + trow] = v;
                    }
                }
            }
        }
    }
    __syncthreads();

    // conv2: 18 outputs (t = t0-1+j), VALU
    float acc2[18];
    {
        float bv = b2[co];
        #pragma unroll
        for (int j = 0; j < 18; ++j) acc2[j] = bv;
        const float4* wp = W2t + co;
        float4 w = *wp;
        for (int cil = 0; cil < 32; ++cil){
            wp += 256;
            float4 wn = *wp;   // overrun lands in w3t, unused
            const float* xp = &hs[(gbase + cil)*20];
            float4 v0 = *(const float4*)(xp);
            float4 v1 = *(const float4*)(xp + 4);
            float4 v2 = *(const float4*)(xp + 8);
            float4 v3 = *(const float4*)(xp + 12);
            float4 v4 = *(const float4*)(xp + 16);
            float xr[20] = {v0.x,v0.y,v0.z,v0.w, v1.x,v1.y,v1.z,v1.w,
                            v2.x,v2.y,v2.z,v2.w, v3.x,v3.y,v3.z,v3.w,
                            v4.x,v4.y,v4.z,v4.w};
            #pragma unroll
            for (int j = 0; j < 18; ++j){
                acc2[j] = fmaf(xr[j],   w.x, acc2[j]);
                acc2[j] = fmaf(xr[j+1], w.y, acc2[j]);
                acc2[j] = fmaf(xr[j+2], w.z, acc2[j]);
            }
            w = wn;
        }
    }
    __syncthreads();
    #pragma unroll
    for (int j = 0; j < 18; ++j){
        int t = t0 - 1 + j;
        hs[co*20 + j] = (t >= 0 && t < T_LEN) ? fmaxf(acc2[j], 0.f) : 0.f;
    }
    __syncthreads();
    // conv3: 16 outputs, VALU
    float acc3[16];
    {
        float bv = b3[co];
        #pragma unroll
        for (int j = 0; j < 16; ++j) acc3[j] = bv;
        const float4* wp = W3t + co;
        float4 w = *wp;
        for (int cil = 0; cil < 32; ++cil){
            wp += 256;
            float4 wn = *wp;   // overrun lands in w1fhi, unused
            const float* xp = &hs[(gbase + cil)*20];
            float4 v0 = *(const float4*)(xp);
            float4 v1 = *(const float4*)(xp + 4);
            float4 v2 = *(const float4*)(xp + 8);
            float4 v3 = *(const float4*)(xp + 12);
            float2 v4 = *(const float2*)(xp + 16);
            float xr[18] = {v0.x,v0.y,v0.z,v0.w, v1.x,v1.y,v1.z,v1.w,
                            v2.x,v2.y,v2.z,v2.w, v3.x,v3.y,v3.z,v3.w, v4.x,v4.y};
            #pragma unroll
            for (int j = 0; j < 16; ++j){
                acc3[j] = fmaf(xr[j],   w.x, acc3[j]);
                acc3[j] = fmaf(xr[j+1], w.y, acc3[j]);
                acc3[j] = fmaf(xr[j+2], w.z, acc3[j]);
            }
            w = wn;
        }
    }
    #pragma unroll
    for (int j = 0; j < 16; ++j){
        float v = fmaxf(acc3[j], 0.f);
        __hip_bfloat16 h = __float2bfloat16(v);
        __hip_bfloat16 l = __float2bfloat16(v - __bfloat162float(h));
        size_t idx = (size_t)(b*T_LEN + t0 + j)*CCH + co;
        ohi[idx] = h;
        olo[idx] = l;
    }
}

// -------- conv4 via MFMA 16x16x32 bf16, split hi/lo (3 passes fused in K loop) --------
__global__ __launch_bounds__(256) void k_conv4(const __hip_bfloat16* __restrict__ hhi,
                                               const __hip_bfloat16* __restrict__ hlo,
                                               const __hip_bfloat16* __restrict__ wfhi,
                                               const __hip_bfloat16* __restrict__ wflo,
                                               const float* __restrict__ bias,
                                               float* __restrict__ ccep){
    __shared__ __align__(16) unsigned char aLds[2][34*512];
    const int gx = blockIdx.x;              // 400 = 16 b * 25 t-tiles
    const int b  = gx / 25;
    const int t0 = (gx - b*25) * 32;
    const int coBase = blockIdx.y << 7;     // 0 or 128
    const int tid = threadIdx.x;
    const int wave = tid >> 6;
    const int l = tid & 63;
    const int l15 = l & 15, lg = l >> 4;

    for (int i = tid; i < 2*1088; i += 256){
        int p = (i >= 1088);
        int c = i - (p ? 1088 : 0);
        int r = c >> 5, c16 = c & 31;
        int t = t0 - 1 + r;
        uint4 v = make_uint4(0u,0u,0u,0u);
        if (t >= 0 && t < T_LEN){
            const __hip_bfloat16* src = (p ? hlo : hhi) + (((size_t)(b*T_LEN + t)) << 8) + (c16 << 3);
            v = *(const uint4*)src;
        }
        int off = (r << 9) + (c16 << 4);
        off ^= (r & 7) << 4;
        *(uint4*)(&aLds[p][off]) = v;
    }
    __syncthreads();

    const int co0 = coBase + (wave << 5);
    f32x4 acc[2][2];
    #pragma unroll
    for (int n = 0; n < 2; ++n){
        int co = co0 + (n << 4) + l15;
        float bq = 0.f;
        if (co < OUT_CH){
            float q = (co < 111) ? (float)(111 - co) : (float)(co - 110);
            bq = bias[co] / q;
        }
        acc[0][n] = f32x4{bq, bq, bq, bq};
        acc[1][n] = f32x4{bq, bq, bq, bq};
    }

    for (int kt = 0; kt < 24; ++kt){
        const int d   = kt >> 3;
        const int cib = (kt & 7) << 6;
        short8 ah[2], al[2];
        #pragma unroll
        for (int m = 0; m < 2; ++m){
            int r = l15 + d + (m << 4);
            int off = (r << 9) + cib + (lg << 4);
            off ^= (r & 7) << 4;
            ah[m] = __builtin_bit_cast(short8, *(const uint4*)(&aLds[0][off]));
            al[m] = __builtin_bit_cast(short8, *(const uint4*)(&aLds[1][off]));
        }
        #pragma unroll
        for (int n = 0; n < 2; ++n){
            int co = co0 + (n << 4) + l15;
            size_t woff = ((size_t)((kt << 2) + lg) << 8) + co;
            short8 bh = __builtin_bit_cast(short8, *(const uint4*)(wfhi + (woff << 3)));
            short8 bl = __builtin_bit_cast(short8, *(const uint4*)(wflo + (woff << 3)));
            #pragma unroll
            for (int m = 0; m < 2; ++m){
                acc[m][n] = __builtin_amdgcn_mfma_f32_16x16x32_bf16(ah[m], bh, acc[m][n], 0, 0, 0);
                acc[m][n] = __builtin_amdgcn_mfma_f32_16x16x32_bf16(ah[m], bl, acc[m][n], 0, 0, 0);
                acc[m][n] = __builtin_amdgcn_mfma_f32_16x16x32_bf16(al[m], bh, acc[m][n], 0, 0, 0);
            }
        }
    }

    #pragma unroll
    for (int m = 0; m < 2; ++m){
        #pragma unroll
        for (int n = 0; n < 2; ++n){
            int co = co0 + (n << 4) + l15;
            #pragma unroll
            for (int j = 0; j < 4; ++j){
                int t = t0 + (m << 4) + (lg << 2) + j;
                ccep[((size_t)(b*T_LEN + t) << 8) + co] = acc[m][n][j];
            }
        }
    }
}

// -------- radix-4 Stockham stage; w1 from 512-entry table, w2/w3 via cmul --------
template<int N4, int Ns, bool INV, bool SKIP3>
__device__ __forceinline__ void r4s(const float2* __restrict__ src,
                                    float2* __restrict__ dst,
                                    const float2* __restrict__ Wt,
                                    int j){
    const int jm = j & (Ns - 1);
    float2 v0 = src[PHI(j)];
    float2 v1 = src[PHI(j + N4)];
    float2 v2 = src[PHI(j + 2*N4)];
    float2 v3 = make_float2(0.f, 0.f);
    if (!SKIP3) v3 = src[PHI(j + 3*N4)];
    if (Ns > 1){
        const int e = jm * (256 / Ns);
        float2 w1 = Wt[PHI(e)];
        if (INV) w1.y = -w1.y;
        float2 w2 = cmul(w1, w1);
        float2 w3 = cmul(w2, w1);
        v1 = cmul(v1, w1);
        v2 = cmul(v2, w2);
        if (!SKIP3) v3 = cmul(v3, w3);
    }
    float2 t0 = make_float2(v0.x + v2.x, v0.y + v2.y);
    float2 t1 = make_float2(v0.x - v2.x, v0.y - v2.y);
    float2 t2, t3;
    if (SKIP3){ t2 = v1; t3 = v1; }
    else {
        t2 = make_float2(v1.x + v3.x, v1.y + v3.y);
        t3 = make_float2(v1.x - v3.x, v1.y - v3.y);
    }
    float2 o0 = make_float2(t0.x + t2.x, t0.y + t2.y);
    float2 o2 = make_float2(t0.x - t2.x, t0.y - t2.y);
    float2 o1, o3;
    if (!INV){
        o1 = make_float2(t1.x + t3.y, t1.y - t3.x);
        o3 = make_float2(t1.x - t3.y, t1.y + t3.x);
    } else {
        o1 = make_float2(t1.x - t3.y, t1.y + t3.x);
        o3 = make_float2(t1.x + t3.y, t1.y - t3.x);
    }
    const int base = ((j - jm) << 2) + jm;
    dst[PHI(base)]          = o0;
    dst[PHI(base + Ns)]     = o1;
    dst[PHI(base + 2*Ns)]   = o2;
    dst[PHI(base + 3*Ns)]   = o3;
}

// -------- per-(b,t): packed fwd FFT(1024) -> merged G/Z-pack -> real-IFFT via 512 -> window --------
__global__ __launch_bounds__(256) void k_filter(const float* __restrict__ ccep,
                                                const float* __restrict__ z,
                                                float* __restrict__ zw){
    __shared__ __align__(16) float2 A[1152];
    __shared__ __align__(16) float2 Bb[1152];
    __shared__ __align__(16) float2 Wt[576];   // W_1024^k, k<512, PHI-padded
    const int t = blockIdx.x;
    const int b = blockIdx.y;
    const int tid = threadIdx.x;
    const float PI2 = 6.283185307179586f;

    for (int j = tid; j < 512; j += 256){
        float s, c;
        __sincosf(-PI2 * (float)j * (1.0f/1024.0f), &s, &c);
        Wt[PHI(j)] = make_float2(c, s);
    }
    const float* crow = &ccep[(b*T_LEN + t)*CSTRIDE];
    #pragma unroll
    for (int r = 0; r < 4; ++r){
        int i = tid + (r << 8);
        float av = (i >= 401 && i < 623) ? crow[i - 401] : 0.f;
        float fv = 0.f;
        if (i < 512){
            int zi = t*HOPSZ + i - 255;
            fv = (zi >= 0 && zi < ZLEN) ? z[b*ZLEN + zi] : 0.f;
        }
        A[PHI(i)] = make_float2(av, fv);
    }
    __syncthreads();

    r4s<256,1,  false,true >(A,  Bb, Wt, tid); __syncthreads();
    r4s<256,4,  false,false>(Bb, A,  Wt, tid); __syncthreads();
    r4s<256,16, false,false>(A,  Bb, Wt, tid); __syncthreads();
    r4s<256,64, false,false>(Bb, A,  Wt, tid); __syncthreads();
    r4s<256,256,false,false>(A,  Bb, Wt, tid); __syncthreads();

    // merged: G[k],G[512-k] -> Z'[k],Z'[512-k] written to A
    {
        const float LOG2_10_DIV10 = 0.33219280948873623f;
        auto unpackG = [&](int i)->float2 {
            float2 P = Bb[PHI(i)];
            float2 Q = Bb[PHI((1024 - i) & 1023)];
            float Are = 0.5f * (P.x + Q.x);
            float Aim = 0.5f * (P.y - Q.y);
            float Fx  = 0.5f * (P.y + Q.y);
            float Fy  = 0.5f * (Q.x - P.x);
            float mag = exp2f(Are * LOG2_10_DIV10) * (1.0f/1024.0f);
            float s, c;
            __sincosf(Aim, &s, &c);
            float Hx = mag * c, Hy = mag * s;
            return make_float2(Fx*Hx + Fy*Hy, Fx*Hy - Fy*Hx);
        };
        int k = tid;
        float2 G  = unpackG(k);
        float2 G2 = unpackG(512 - k);
        float sx = G.x + G2.x, sy = G.y - G2.y;
        float dx = G.x - G2.x, dy = G.y + G2.y;
        float2 V = Wt[PHI(k)];
        float ux = dx*V.x + dy*V.y;
        float uy = dy*V.x - dx*V.y;
        A[PHI(k)] = make_float2(sx - uy, sy + ux);
        if (k){
            A[PHI(512 - k)] = make_float2(sx + uy, ux - sy);
        } else {
            float2 G3 = unpackG(256);
            A[PHI(256)] = make_float2(2.f*G3.x, -2.f*G3.y);
        }
    }
    __syncthreads();

    if (tid < 128) r4s<128,1, true,false>(A,  Bb, Wt, tid);
    __syncthreads();
    if (tid < 128) r4s<128,4, true,false>(Bb, A,  Wt, tid);
    __syncthreads();
    if (tid < 128) r4s<128,16,true,false>(A,  Bb, Wt, tid);
    __syncthreads();
    if (tid < 128) r4s<128,64,true,false>(Bb, A,  Wt, tid);
    __syncthreads();
    {
        int j = tid;
        float2 u = A[PHI(j)];
        float2 v = A[PHI(j + 256)];
        float2 w = Wt[PHI(2*j)];
        w.y = -w.y;
        float2 vv = cmul(v, w);
        Bb[PHI(j)]       = make_float2(u.x + vv.x, u.y + vv.y);
        Bb[PHI(j + 256)] = make_float2(u.x - vv.x, u.y - vv.y);
    }
    __syncthreads();

    float* zrow = &zw[(size_t)(b*T_LEN + t)*512];
    #pragma unroll
    for (int r = 0; r < 2; ++r){
        int n = tid + (r << 8);
        int m = (511 - n) >> 1;
        float2 zv = Bb[PHI(m)];
        float yv = (n & 1) ? zv.x : zv.y;
        float wv = 0.5f * (1.0f - __cosf(PI2 * (float)n * (1.0f/512.0f)));
        zrow[n] = yv * wv;
    }
}

// -------- OLA + clip --------
__global__ __launch_bounds__(256) void k_ola(const float* __restrict__ zw,
                                             float* __restrict__ out){
    const int t = blockIdx.x;
    const int b = blockIdx.y;
    const int h = threadIdx.x;
    const int tm = (t + T_LEN - 1) % T_LEN;
    float v = zw[(size_t)(b*T_LEN + t)*512 + h]
            + zw[(size_t)(b*T_LEN + tm)*512 + 256 + h];
    v = fminf(fmaxf(v, -1.0f), 1.0f);
    out[(size_t)b*ZLEN + t*HOPSZ + h] = v;
}

extern "C" void kernel_launch(void* const* d_in, const int* in_sizes, int n_in,
                              void* d_out, int out_size, void* d_ws, size_t ws_size,
                              hipStream_t stream){
    const float* x  = (const float*)d_in[0];
    const float* z  = (const float*)d_in[1];
    const float* W1 = (const float*)d_in[2];
    const float* b1 = (const float*)d_in[3];
    const float* W2 = (const float*)d_in[4];
    const float* b2 = (const float*)d_in[5];
    const float* W3 = (const float*)d_in[6];
    const float* b3 = (const float*)d_in[7];
    const float* W4 = (const float*)d_in[8];
    const float* b4 = (const float*)d_in[9];
    float* out = (float*)d_out;
    float* ws  = (float*)d_ws;

    // layout (floats):
    float* ccep = ws;                                         // 3,276,800
    __hip_bfloat16* h3hi = (__hip_bfloat16*)(ws + 3276800);   // conv123 out planes
    __hip_bfloat16* h3lo = h3hi + 3276800;
    float* zwb  = ws + 6553600;                               // 6,553,600
    // weights in FRONT of zwb (read by convs, overwritten later by k_filter)
    float4* w2t = (float4*)(zwb);                             //  8192 f4
    float4* w3t = (float4*)(zwb + 32768);                     //  8192 f4
    __hip_bfloat16* w1fhi = (__hip_bfloat16*)(zwb + 65536);   // 73728 bf16
    __hip_bfloat16* w1flo = (__hip_bfloat16*)(zwb + 102400);  // 73728 bf16
    __hip_bfloat16* wfhi  = (__hip_bfloat16*)(zwb + 139264);  // 196608 bf16
    __hip_bfloat16* wflo  = (__hip_bfloat16*)(zwb + 237568);

    dim3 blk(256);
    dim3 gwt(768, 4);
    dim3 gconv(T_LEN/16, B_SZ);       // (50,16)
    dim3 gc4(400, 2);
    dim3 gf(T_LEN, B_SZ);             // (800,16)

    k_wtrans<<<gwt, blk, 0, stream>>>(W1, W2, W3, W4, w2t, w3t, w1fhi, w1flo, wfhi, wflo);
    k_conv123<<<gconv, blk, 0, stream>>>(x, w1fhi, w1flo, b1, w2t, b2, w3t, b3, h3hi, h3lo);
    k_conv4<<<gc4, blk, 0, stream>>>(h3hi, h3lo, wfhi, wflo, b4, ccep);
    k_filter<<<gf, blk, 0, stream>>>(ccep, z, zwb);
    k_ola<<<gf, blk, 0, stream>>>(zwb, out);
}

// Round 19
// 140.732 us; speedup vs baseline: 1.0237x; 1.0237x over previous
//
#include <hip/hip_runtime.h>
#include <hip/hip_bf16.h>

#define T_LEN 800
#define B_SZ  16
#define D_IN  80
#define CCH   256
#define OUT_CH 222
#define HOPSZ 256
#define WINSZ 512
#define ZLEN  (T_LEN*HOPSZ)   // 204800
#define CSTRIDE 256           // ccep row stride ([t][co] layout)
#define XSTR 104              // bf16 row stride for staged x

#define PHI(i) ((i) + ((i)>>3))

typedef short short8 __attribute__((ext_vector_type(8)));
typedef float f32x4 __attribute__((ext_vector_type(4)));

__device__ __forceinline__ float2 cmul(float2 a, float2 b){
    return make_float2(a.x*b.x - a.y*b.y, a.x*b.y + a.y*b.x);
}

// -------- weight transforms --------
__global__ __launch_bounds__(256) void k_wtrans(const float* __restrict__ W1,
                                                const float* __restrict__ W2,
                                                const float* __restrict__ W3,
                                                const float* __restrict__ W4,
                                                float4* __restrict__ w2t,
                                                float4* __restrict__ w3t,
                                                __hip_bfloat16* __restrict__ w1fhi,
                                                __hip_bfloat16* __restrict__ w1flo,
                                                __hip_bfloat16* __restrict__ wfhi,
                                                __hip_bfloat16* __restrict__ wflo){
    const int i = blockIdx.x*256 + threadIdx.x;
    switch (blockIdx.y){
    case 0: if (i < 32*256){
        int cil = i >> 8, co = i & 255;
        const float* s = &W2[(co*32 + cil)*3];
        w2t[i] = make_float4(s[0], s[1], s[2], 0.f);
    } break;
    case 1: if (i < 32*256){
        int cil = i >> 8, co = i & 255;
        const float* s = &W3[(co*32 + cil)*3];
        w3t[i] = make_float4(s[0], s[1], s[2], 0.f);
    } break;
    case 2: if (i < 9*4*256*8){
        int e  = i & 7;
        int co = (i >> 3) & 255;
        int lg = (i >> 11) & 3;
        int dk = i >> 13;            // 0..8
        int d  = dk / 3, kt = dk - 3*d;
        int ci = kt*32 + lg*8 + e;
        float w = (ci < 80) ? W1[(co*80 + ci)*3 + d] : 0.f;
        __hip_bfloat16 h = __float2bfloat16(w);
        __hip_bfloat16 l = __float2bfloat16(w - __bfloat162float(h));
        w1fhi[i] = h;
        w1flo[i] = l;
    } break;
    default: if (i < 768*256){
        int k = i >> 8, co = i & 255;
        int d = k >> 8, ci = k & 255;
        float w = 0.f;
        if (co < OUT_CH){
            float q = (co < 111) ? (float)(111 - co) : (float)(co - 110);
            w = W4[(co*256 + ci)*3 + d] / q;   // fold 1/quef into weights
        }
        __hip_bfloat16 h = __float2bfloat16(w);
        __hip_bfloat16 l = __float2bfloat16(w - __bfloat162float(h));
        int kt = k >> 5, g = (k >> 3) & 3, e = k & 7;
        int idx = ((kt*4 + g)*256 + co)*8 + e;
        wfhi[idx] = h;
        wflo[idx] = l;
    } break;
    }
}

// -------- fused conv1(MFMA)+conv2+conv3: x -> bf16 hi/lo planes (R15-proven) --------
__global__ __launch_bounds__(256) void k_conv123(const float* __restrict__ x,
                                                 const __hip_bfloat16* __restrict__ w1fhi,
                                                 const __hip_bfloat16* __restrict__ w1flo,
                                                 const float* __restrict__ b1,
                                                 const float4* __restrict__ W2t,
                                                 const float* __restrict__ b2,
                                                 const float4* __restrict__ W3t,
                                                 const float* __restrict__ b3,
                                                 __hip_bfloat16* __restrict__ ohi,
                                                 __hip_bfloat16* __restrict__ olo){
    __shared__ __align__(16) __hip_bfloat16 xhi[34*XSTR];  // x rows t0-3..t0+30
    __shared__ __align__(16) __hip_bfloat16 xlo[34*XSTR];
    __shared__ __align__(16) float hs[256*20];             // [co][t-local]
    const int t0 = blockIdx.x * 16;
    const int b  = blockIdx.y;
    const int tid = threadIdx.x;
    const int co = tid;
    const int gbase = (co >> 5) << 5;
    const int wave = tid >> 6;
    const int l = tid & 63;
    const int l15 = l & 15, lg4 = l >> 4;

    // stage x as split bf16; pad columns [80,104) zeroed
    for (int i = tid; i < 34*XSTR; i += 256){
        int rr = i / XSTR, c = i - rr*XSTR;
        float v = 0.f;
        if (c < 80){
            int t = t0 - 3 + rr;
            v = (t >= 0 && t < T_LEN) ? x[(b*T_LEN + t)*D_IN + c] : 0.f;
        }
        __hip_bfloat16 h = __float2bfloat16(v);
        xhi[i] = h;
        xlo[i] = __float2bfloat16(v - __bfloat162float(h));
    }
    __syncthreads();

    // conv1 via MFMA
    {
        f32x4 acc1[2][4];
        #pragma unroll
        for (int n = 0; n < 4; ++n){
            float bv = b1[(wave << 6) + (n << 4) + l15];
            acc1[0][n] = f32x4{bv, bv, bv, bv};
            acc1[1][n] = f32x4{bv, bv, bv, bv};
        }
        #pragma unroll
        for (int d = 0; d < 3; ++d){
            #pragma unroll
            for (int kt = 0; kt < 3; ++kt){
                short8 ah[2], al[2];
                #pragma unroll
                for (int m = 0; m < 2; ++m){
                    int off = ((m << 4) + l15 + d)*XSTR + kt*32 + lg4*8;
                    ah[m] = __builtin_bit_cast(short8, *(const uint4*)(xhi + off));
                    al[m] = __builtin_bit_cast(short8, *(const uint4*)(xlo + off));
                }
                #pragma unroll
                for (int n = 0; n < 4; ++n){
                    int co_n = (wave << 6) + (n << 4) + l15;
                    int wo = ((((d*3 + kt)*4 + lg4) << 8) + co_n) << 3;
                    short8 bh = __builtin_bit_cast(short8, *(const uint4*)(w1fhi + wo));
                    short8 bl = __builtin_bit_cast(short8, *(const uint4*)(w1flo + wo));
                    #pragma unroll
                    for (int m = 0; m < 2; ++m){
                        acc1[m][n] = __builtin_amdgcn_mfma_f32_16x16x32_bf16(ah[m], bh, acc1[m][n], 0, 0, 0);
                        acc1[m][n] = __builtin_amdgcn_mfma_f32_16x16x32_bf16(ah[m], bl, acc1[m][n], 0, 0, 0);
                        acc1[m][n] = __builtin_amdgcn_mfma_f32_16x16x32_bf16(al[m], bh, acc1[m][n], 0, 0, 0);
                    }
                }
            }
        }
        // writeback: relu + zero-mask outside [0,T); hs[co][trow], trow<20
        #pragma unroll
        for (int m = 0; m < 2; ++m){
            #pragma unroll
            for (int n = 0; n < 4; ++n){
                int co_n = (wave << 6) + (n << 4) + l15;
                #pragma unroll
                for (int j = 0; j < 4; ++j){
                    int trow = (m << 4) + (lg4 << 2) + j;
                    if (trow < 20){
                        int t = t0 - 2 + trow;
                        float v = (t >= 0 && t < T_LEN) ? fmaxf(acc1[m][n][j], 0.f) : 0.f;
                        hs[co_n*20 + trow] = v;
                    }
                }
            }
        }
    }
    __syncthreads();

    // conv2: 18 outputs (t = t0-1+j), VALU
    float acc2[18];
    {
        float bv = b2[co];
        #pragma unroll
        for (int j = 0; j < 18; ++j) acc2[j] = bv;
        const float4* wp = W2t + co;
        float4 w = *wp;
        for (int cil = 0; cil < 32; ++cil){
            wp += 256;
            float4 wn = *wp;   // overrun lands in w3t, unused
            const float* xp = &hs[(gbase + cil)*20];
            float4 v0 = *(const float4*)(xp);
            float4 v1 = *(const float4*)(xp + 4);
            float4 v2 = *(const float4*)(xp + 8);
            float4 v3 = *(const float4*)(xp + 12);
            float4 v4 = *(const float4*)(xp + 16);
            float xr[20] = {v0.x,v0.y,v0.z,v0.w, v1.x,v1.y,v1.z,v1.w,
                            v2.x,v2.y,v2.z,v2.w, v3.x,v3.y,v3.z,v3.w,
                            v4.x,v4.y,v4.z,v4.w};
            #pragma unroll
            for (int j = 0; j < 18; ++j){
                acc2[j] = fmaf(xr[j],   w.x, acc2[j]);
                acc2[j] = fmaf(xr[j+1], w.y, acc2[j]);
                acc2[j] = fmaf(xr[j+2], w.z, acc2[j]);
            }
            w = wn;
        }
    }
    __syncthreads();
    #pragma unroll
    for (int j = 0; j < 18; ++j){
        int t = t0 - 1 + j;
        hs[co*20 + j] = (t >= 0 && t < T_LEN) ? fmaxf(acc2[j], 0.f) : 0.f;
    }
    __syncthreads();
    // conv3: 16 outputs, VALU
    float acc3[16];
    {
        float bv = b3[co];
        #pragma unroll
        for (int j = 0; j < 16; ++j) acc3[j] = bv;
        const float4* wp = W3t + co;
        float4 w = *wp;
        for (int cil = 0; cil < 32; ++cil){
            wp += 256;
            float4 wn = *wp;   // overrun lands in w1fhi, unused
            const float* xp = &hs[(gbase + cil)*20];
            float4 v0 = *(const float4*)(xp);
            float4 v1 = *(const float4*)(xp + 4);
            float4 v2 = *(const float4*)(xp + 8);
            float4 v3 = *(const float4*)(xp + 12);
            float2 v4 = *(const float2*)(xp + 16);
            float xr[18] = {v0.x,v0.y,v0.z,v0.w, v1.x,v1.y,v1.z,v1.w,
                            v2.x,v2.y,v2.z,v2.w, v3.x,v3.y,v3.z,v3.w, v4.x,v4.y};
            #pragma unroll
            for (int j = 0; j < 16; ++j){
                acc3[j] = fmaf(xr[j],   w.x, acc3[j]);
                acc3[j] = fmaf(xr[j+1], w.y, acc3[j]);
                acc3[j] = fmaf(xr[j+2], w.z, acc3[j]);
            }
            w = wn;
        }
    }
    #pragma unroll
    for (int j = 0; j < 16; ++j){
        float v = fmaxf(acc3[j], 0.f);
        __hip_bfloat16 h = __float2bfloat16(v);
        __hip_bfloat16 l = __float2bfloat16(v - __bfloat162float(h));
        size_t idx = (size_t)(b*T_LEN + t0 + j)*CCH + co;
        ohi[idx] = h;
        olo[idx] = l;
    }
}

// -------- conv4 via MFMA 16x16x32 bf16, split hi/lo (unchanged) --------
__global__ __launch_bounds__(256) void k_conv4(const __hip_bfloat16* __restrict__ hhi,
                                               const __hip_bfloat16* __restrict__ hlo,
                                               const __hip_bfloat16* __restrict__ wfhi,
                                               const __hip_bfloat16* __restrict__ wflo,
                                               const float* __restrict__ bias,
                                               float* __restrict__ ccep){
    __shared__ __align__(16) unsigned char aLds[2][34*512];
    const int gx = blockIdx.x;              // 400 = 16 b * 25 t-tiles
    const int b  = gx / 25;
    const int t0 = (gx - b*25) * 32;
    const int coBase = blockIdx.y << 7;     // 0 or 128
    const int tid = threadIdx.x;
    const int wave = tid >> 6;
    const int l = tid & 63;
    const int l15 = l & 15, lg = l >> 4;

    for (int i = tid; i < 2*1088; i += 256){
        int p = (i >= 1088);
        int c = i - (p ? 1088 : 0);
        int r = c >> 5, c16 = c & 31;
        int t = t0 - 1 + r;
        uint4 v = make_uint4(0u,0u,0u,0u);
        if (t >= 0 && t < T_LEN){
            const __hip_bfloat16* src = (p ? hlo : hhi) + (((size_t)(b*T_LEN + t)) << 8) + (c16 << 3);
            v = *(const uint4*)src;
        }
        int off = (r << 9) + (c16 << 4);
        off ^= (r & 7) << 4;
        *(uint4*)(&aLds[p][off]) = v;
    }
    __syncthreads();

    const int co0 = coBase + (wave << 5);
    f32x4 acc[2][2];
    #pragma unroll
    for (int n = 0; n < 2; ++n){
        int co = co0 + (n << 4) + l15;
        float bq = 0.f;
        if (co < OUT_CH){
            float q = (co < 111) ? (float)(111 - co) : (float)(co - 110);
            bq = bias[co] / q;
        }
        acc[0][n] = f32x4{bq, bq, bq, bq};
        acc[1][n] = f32x4{bq, bq, bq, bq};
    }

    for (int kt = 0; kt < 24; ++kt){
        const int d   = kt >> 3;
        const int cib = (kt & 7) << 6;
        short8 ah[2], al[2];
        #pragma unroll
        for (int m = 0; m < 2; ++m){
            int r = l15 + d + (m << 4);
            int off = (r << 9) + cib + (lg << 4);
            off ^= (r & 7) << 4;
            ah[m] = __builtin_bit_cast(short8, *(const uint4*)(&aLds[0][off]));
            al[m] = __builtin_bit_cast(short8, *(const uint4*)(&aLds[1][off]));
        }
        #pragma unroll
        for (int n = 0; n < 2; ++n){
            int co = co0 + (n << 4) + l15;
            size_t woff = ((size_t)((kt << 2) + lg) << 8) + co;
            short8 bh = __builtin_bit_cast(short8, *(const uint4*)(wfhi + (woff << 3)));
            short8 bl = __builtin_bit_cast(short8, *(const uint4*)(wflo + (woff << 3)));
            #pragma unroll
            for (int m = 0; m < 2; ++m){
                acc[m][n] = __builtin_amdgcn_mfma_f32_16x16x32_bf16(ah[m], bh, acc[m][n], 0, 0, 0);
                acc[m][n] = __builtin_amdgcn_mfma_f32_16x16x32_bf16(ah[m], bl, acc[m][n], 0, 0, 0);
                acc[m][n] = __builtin_amdgcn_mfma_f32_16x16x32_bf16(al[m], bh, acc[m][n], 0, 0, 0);
            }
        }
    }

    #pragma unroll
    for (int m = 0; m < 2; ++m){
        #pragma unroll
        for (int n = 0; n < 2; ++n){
            int co = co0 + (n << 4) + l15;
            #pragma unroll
            for (int j = 0; j < 4; ++j){
                int t = t0 + (m << 4) + (lg << 2) + j;
                ccep[((size_t)(b*T_LEN + t) << 8) + co] = acc[m][n][j];
            }
        }
    }
}

// -------- radix-4 Stockham stage; w1 from 512-entry table, w2/w3 via cmul --------
template<int N4, int Ns, bool INV, bool SKIP3>
__device__ __forceinline__ void r4s(const float2* __restrict__ src,
                                    float2* __restrict__ dst,
                                    const float2* __restrict__ Wt,
                                    int j){
    const int jm = j & (Ns - 1);
    float2 v0 = src[PHI(j)];
    float2 v1 = src[PHI(j + N4)];
    float2 v2 = src[PHI(j + 2*N4)];
    float2 v3 = make_float2(0.f, 0.f);
    if (!SKIP3) v3 = src[PHI(j + 3*N4)];
    if (Ns > 1){
        const int e = jm * (256 / Ns);
        float2 w1 = Wt[PHI(e)];
        if (INV) w1.y = -w1.y;
        float2 w2 = cmul(w1, w1);
        float2 w3 = cmul(w2, w1);
        v1 = cmul(v1, w1);
        v2 = cmul(v2, w2);
        if (!SKIP3) v3 = cmul(v3, w3);
    }
    float2 t0 = make_float2(v0.x + v2.x, v0.y + v2.y);
    float2 t1 = make_float2(v0.x - v2.x, v0.y - v2.y);
    float2 t2, t3;
    if (SKIP3){ t2 = v1; t3 = v1; }
    else {
        t2 = make_float2(v1.x + v3.x, v1.y + v3.y);
        t3 = make_float2(v1.x - v3.x, v1.y - v3.y);
    }
    float2 o0 = make_float2(t0.x + t2.x, t0.y + t2.y);
    float2 o2 = make_float2(t0.x - t2.x, t0.y - t2.y);
    float2 o1, o3;
    if (!INV){
        o1 = make_float2(t1.x + t3.y, t1.y - t3.x);
        o3 = make_float2(t1.x - t3.y, t1.y + t3.x);
    } else {
        o1 = make_float2(t1.x - t3.y, t1.y + t3.x);
        o3 = make_float2(t1.x + t3.y, t1.y - t3.x);
    }
    const int base = ((j - jm) << 2) + jm;
    dst[PHI(base)]          = o0;
    dst[PHI(base + Ns)]     = o1;
    dst[PHI(base + 2*Ns)]   = o2;
    dst[PHI(base + 3*Ns)]   = o3;
}

// -------- per-(b,t): fused-load fwd FFT -> merged G/Z-pack -> inv FFT -> fused r2+window+store --------
__global__ __launch_bounds__(256) void k_filter(const float* __restrict__ ccep,
                                                const float* __restrict__ z,
                                                float* __restrict__ zw){
    __shared__ __align__(16) float2 A[1152];
    __shared__ __align__(16) float2 Bb[1152];
    __shared__ __align__(16) float2 Wt[576];   // W_1024^k, k<512, PHI-padded
    const int t = blockIdx.x;
    const int b = blockIdx.y;
    const int tid = threadIdx.x;
    const float PI2 = 6.283185307179586f;

    for (int j = tid; j < 512; j += 256){
        float s, c;
        __sincosf(-PI2 * (float)j * (1.0f/1024.0f), &s, &c);
        Wt[PHI(j)] = make_float2(c, s);
    }
    // fused load + forward stage-1 (Ns=1, SKIP3: p[768..1023]=0) — value-identical to r4s<256,1,false,true>
    {
        const float* crow = &ccep[(b*T_LEN + t)*CSTRIDE];
        auto gen = [&](int i)->float2 {
            float av = (i >= 401 && i < 623) ? crow[i - 401] : 0.f;
            float fv = 0.f;
            if (i < 512){
                int zi = t*HOPSZ + i - 255;
                fv = (zi >= 0 && zi < ZLEN) ? z[b*ZLEN + zi] : 0.f;
            }
            return make_float2(av, fv);
        };
        int j = tid;
        float2 v0 = gen(j);
        float2 v1 = gen(j + 256);
        float2 v2 = gen(j + 512);
        float2 t0 = make_float2(v0.x + v2.x, v0.y + v2.y);
        float2 t1 = make_float2(v0.x - v2.x, v0.y - v2.y);
        int base = PHI(4*j);   // 4j..4j+3 contiguous in PHI space
        Bb[base]     = make_float2(t0.x + v1.x, t0.y + v1.y);
        Bb[base + 1] = make_float2(t1.x + v1.y, t1.y - v1.x);
        Bb[base + 2] = make_float2(t0.x - v1.x, t0.y - v1.y);
        Bb[base + 3] = make_float2(t1.x - v1.y, t1.y + v1.x);
    }
    __syncthreads();

    r4s<256,4,  false,false>(Bb, A,  Wt, tid); __syncthreads();
    r4s<256,16, false,false>(A,  Bb, Wt, tid); __syncthreads();
    r4s<256,64, false,false>(Bb, A,  Wt, tid); __syncthreads();
    r4s<256,256,false,false>(A,  Bb, Wt, tid); __syncthreads();

    // merged: G[k],G[512-k] -> Z'[k],Z'[512-k] written to A
    {
        const float LOG2_10_DIV10 = 0.33219280948873623f;
        auto unpackG = [&](int i)->float2 {
            float2 P = Bb[PHI(i)];
            float2 Q = Bb[PHI((1024 - i) & 1023)];
            float Are = 0.5f * (P.x + Q.x);
            float Aim = 0.5f * (P.y - Q.y);
            float Fx  = 0.5f * (P.y + Q.y);
            float Fy  = 0.5f * (Q.x - P.x);
            float mag = exp2f(Are * LOG2_10_DIV10) * (1.0f/1024.0f);
            float s, c;
            __sincosf(Aim, &s, &c);
            float Hx = mag * c, Hy = mag * s;
            return make_float2(Fx*Hx + Fy*Hy, Fx*Hy - Fy*Hx);
        };
        int k = tid;
        float2 G  = unpackG(k);
        float2 G2 = unpackG(512 - k);
        float sx = G.x + G2.x, sy = G.y - G2.y;
        float dx = G.x - G2.x, dy = G.y + G2.y;
        float2 V = Wt[PHI(k)];
        float ux = dx*V.x + dy*V.y;
        float uy = dy*V.x - dx*V.y;
        A[PHI(k)] = make_float2(sx - uy, sy + ux);
        if (k){
            A[PHI(512 - k)] = make_float2(sx + uy, ux - sy);
        } else {
            float2 G3 = unpackG(256);
            A[PHI(256)] = make_float2(2.f*G3.x, -2.f*G3.y);
        }
    }
    __syncthreads();

    if (tid < 128) r4s<128,1, true,false>(A,  Bb, Wt, tid);
    __syncthreads();
    if (tid < 128) r4s<128,4, true,false>(Bb, A,  Wt, tid);
    __syncthreads();
    if (tid < 128) r4s<128,16,true,false>(A,  Bb, Wt, tid);
    __syncthreads();
    if (tid < 128) r4s<128,64,true,false>(Bb, A,  Wt, tid);
    __syncthreads();

    // fused final radix-2 + Hann + store; only z[0..255] is consumed.
    // Windows computed with DIRECT __cosf (identical to R15's proven path).
    {
        int j = tid;
        float2 u = A[PHI(j)];
        float2 v = A[PHI(j + 256)];
        float2 w = Wt[PHI(2*j)];
        w.y = -w.y;
        float2 vv = cmul(v, w);
        float zx = u.x + vv.x, zy = u.y + vv.y;   // z[j]
        int n1 = 511 - 2*j;    // odd  -> Re z[j]  (m=(511-n1)>>1 = j)
        int n2 = 510 - 2*j;    // even -> Im z[j]  (m=(511-n2)>>1 = j)
        float wv1 = 0.5f * (1.0f - __cosf(PI2 * (float)n1 * (1.0f/512.0f)));
        float wv2 = 0.5f * (1.0f - __cosf(PI2 * (float)n2 * (1.0f/512.0f)));
        float* zrow = &zw[(size_t)(b*T_LEN + t)*512];
        zrow[n1] = zx * wv1;
        zrow[n2] = zy * wv2;
    }
}

// -------- OLA + clip --------
__global__ __launch_bounds__(256) void k_ola(const float* __restrict__ zw,
                                             float* __restrict__ out){
    const int t = blockIdx.x;
    const int b = blockIdx.y;
    const int h = threadIdx.x;
    const int tm = (t + T_LEN - 1) % T_LEN;
    float v = zw[(size_t)(b*T_LEN + t)*512 + h]
            + zw[(size_t)(b*T_LEN + tm)*512 + 256 + h];
    v = fminf(fmaxf(v, -1.0f), 1.0f);
    out[(size_t)b*ZLEN + t*HOPSZ + h] = v;
}

extern "C" void kernel_launch(void* const* d_in, const int* in_sizes, int n_in,
                              void* d_out, int out_size, void* d_ws, size_t ws_size,
                              hipStream_t stream){
    const float* x  = (const float*)d_in[0];
    const float* z  = (const float*)d_in[1];
    const float* W1 = (const float*)d_in[2];
    const float* b1 = (const float*)d_in[3];
    const float* W2 = (const float*)d_in[4];
    const float* b2 = (const float*)d_in[5];
    const float* W3 = (const float*)d_in[6];
    const float* b3 = (const float*)d_in[7];
    const float* W4 = (const float*)d_in[8];
    const float* b4 = (const float*)d_in[9];
    float* out = (float*)d_out;
    float* ws  = (float*)d_ws;

    // layout (floats):
    float* ccep = ws;                                         // 3,276,800
    __hip_bfloat16* h3hi = (__hip_bfloat16*)(ws + 3276800);   // conv123 out planes
    __hip_bfloat16* h3lo = h3hi + 3276800;
    float* zwb  = ws + 6553600;                               // 6,553,600
    // weights in FRONT of zwb (read by convs, overwritten later by k_filter)
    float4* w2t = (float4*)(zwb);                             //  8192 f4
    float4* w3t = (float4*)(zwb + 32768);                     //  8192 f4
    __hip_bfloat16* w1fhi = (__hip_bfloat16*)(zwb + 65536);   // 73728 bf16
    __hip_bfloat16* w1flo = (__hip_bfloat16*)(zwb + 102400);  // 73728 bf16
    __hip_bfloat16* wfhi  = (__hip_bfloat16*)(zwb + 139264);  // 196608 bf16
    __hip_bfloat16* wflo  = (__hip_bfloat16*)(zwb + 237568);

    dim3 blk(256);
    dim3 gwt(768, 4);
    dim3 gconv(T_LEN/16, B_SZ);       // (50,16)
    dim3 gc4(400, 2);
    dim3 gf(T_LEN, B_SZ);             // (800,16)

    k_wtrans<<<gwt, blk, 0, stream>>>(W1, W2, W3, W4, w2t, w3t, w1fhi, w1flo, wfhi, wflo);
    k_conv123<<<gconv, blk, 0, stream>>>(x, w1fhi, w1flo, b1, w2t, b2, w3t, b3, h3hi, h3lo);
    k_conv4<<<gc4, blk, 0, stream>>>(h3hi, h3lo, wfhi, wflo, b4, ccep);
    k_filter<<<gf, blk, 0, stream>>>(ccep, z, zwb);
    k_ola<<<gf, blk, 0, stream>>>(zwb, out);
}

// Round 21
// 126.543 us; speedup vs baseline: 1.1385x; 1.1121x over previous
//
#include <hip/hip_runtime.h>
#include <hip/hip_bf16.h>

#define T_LEN 800
#define B_SZ  16
#define D_IN  80
#define CCH   256
#define OUT_CH 222
#define HOPSZ 256
#define WINSZ 512
#define ZLEN  (T_LEN*HOPSZ)   // 204800
#define CSTRIDE 256           // ccep row stride ([t][co] layout)
#define XSTR 104              // bf16 row stride for staged x

#define PHI(i) ((i) + ((i)>>3))

typedef short short8 __attribute__((ext_vector_type(8)));
typedef float f32x4 __attribute__((ext_vector_type(4)));

__device__ __forceinline__ float2 cmul(float2 a, float2 b){
    return make_float2(a.x*b.x - a.y*b.y, a.x*b.y + a.y*b.x);
}

// -------- weight transforms --------
// w1f: conv1 fragment-split (proven layout).  w2f/w3f: grouped-conv fragment tables
// idx = ((((g*2+n)*3 + d)*4 + lg)*16 + c15)*8 + e ; co = g*32+n*16+c15, cil = lg*8+e.
// wf4: conv4 table (proven layout).
__global__ __launch_bounds__(256) void k_wtrans(const float* __restrict__ W1,
                                                const float* __restrict__ W2,
                                                const float* __restrict__ W3,
                                                const float* __restrict__ W4,
                                                __hip_bfloat16* __restrict__ w1fhi,
                                                __hip_bfloat16* __restrict__ w1flo,
                                                __hip_bfloat16* __restrict__ w2fhi,
                                                __hip_bfloat16* __restrict__ w2flo,
                                                __hip_bfloat16* __restrict__ w3fhi,
                                                __hip_bfloat16* __restrict__ w3flo,
                                                __hip_bfloat16* __restrict__ wfhi,
                                                __hip_bfloat16* __restrict__ wflo){
    const int i = blockIdx.x*256 + threadIdx.x;
    switch (blockIdx.y){
    case 0: if (i < 16*3*4*16*8){     // 24576: w2 fragment table
        int e   = i & 7;
        int c15 = (i >> 3) & 15;
        int lg  = (i >> 7) & 3;
        int t   = i >> 9;
        int d   = t % 3;
        int gn  = t / 3;              // 0..15
        int co  = (gn >> 1)*32 + (gn & 1)*16 + c15;
        int cil = lg*8 + e;
        float w = W2[(co*32 + cil)*3 + d];
        __hip_bfloat16 h = __float2bfloat16(w);
        w2fhi[i] = h;
        w2flo[i] = __float2bfloat16(w - __bfloat162float(h));
    } break;
    case 1: if (i < 16*3*4*16*8){     // 24576: w3 fragment table
        int e   = i & 7;
        int c15 = (i >> 3) & 15;
        int lg  = (i >> 7) & 3;
        int t   = i >> 9;
        int d   = t % 3;
        int gn  = t / 3;
        int co  = (gn >> 1)*32 + (gn & 1)*16 + c15;
        int cil = lg*8 + e;
        float w = W3[(co*32 + cil)*3 + d];
        __hip_bfloat16 h = __float2bfloat16(w);
        w3fhi[i] = h;
        w3flo[i] = __float2bfloat16(w - __bfloat162float(h));
    } break;
    case 2: if (i < 9*4*256*8){       // 73728: w1 fragment table (proven)
        int e  = i & 7;
        int co = (i >> 3) & 255;
        int lg = (i >> 11) & 3;
        int dk = i >> 13;             // 0..8
        int d  = dk / 3, kt = dk - 3*d;
        int ci = kt*32 + lg*8 + e;
        float w = (ci < 80) ? W1[(co*80 + ci)*3 + d] : 0.f;
        __hip_bfloat16 h = __float2bfloat16(w);
        w1fhi[i] = h;
        w1flo[i] = __float2bfloat16(w - __bfloat162float(h));
    } break;
    default: if (i < 768*256){        // 196608: conv4 table (proven)
        int k = i >> 8, co = i & 255;
        int d = k >> 8, ci = k & 255;
        float w = 0.f;
        if (co < OUT_CH){
            float q = (co < 111) ? (float)(111 - co) : (float)(co - 110);
            w = W4[(co*256 + ci)*3 + d] / q;   // fold 1/quef into weights
        }
        __hip_bfloat16 h = __float2bfloat16(w);
        __hip_bfloat16 l = __float2bfloat16(w - __bfloat162float(h));
        int kt = k >> 5, g = (k >> 3) & 3, e = k & 7;
        int idx = ((kt*4 + g)*256 + co)*8 + e;
        wfhi[idx] = h;
        wflo[idx] = l;
    } break;
    }
}

// -------- conv1 via MFMA, t-tile 32 (all output rows valid): x -> h1 split-bf16 planes --------
__global__ __launch_bounds__(256) void k_conv1m(const float* __restrict__ x,
                                                const __hip_bfloat16* __restrict__ w1fhi,
                                                const __hip_bfloat16* __restrict__ w1flo,
                                                const float* __restrict__ b1,
                                                __hip_bfloat16* __restrict__ ohi,
                                                __hip_bfloat16* __restrict__ olo){
    __shared__ __align__(16) __hip_bfloat16 xhi[34*XSTR];  // rows t0-1 .. t0+32
    __shared__ __align__(16) __hip_bfloat16 xlo[34*XSTR];
    const int t0 = blockIdx.x * 32;
    const int b  = blockIdx.y;
    const int tid = threadIdx.x;
    const int wave = tid >> 6;
    const int l = tid & 63;
    const int l15 = l & 15, lg4 = l >> 4;

    // stage x as split bf16; pad columns [80,104) zeroed; row rr ~ t = t0-1+rr
    for (int i = tid; i < 34*XSTR; i += 256){
        int rr = i / XSTR, c = i - rr*XSTR;
        float v = 0.f;
        if (c < 80){
            int t = t0 - 1 + rr;
            v = (t >= 0 && t < T_LEN) ? x[(b*T_LEN + t)*D_IN + c] : 0.f;
        }
        __hip_bfloat16 h = __float2bfloat16(v);
        xhi[i] = h;
        xlo[i] = __float2bfloat16(v - __bfloat162float(h));
    }
    __syncthreads();

    // conv1 MFMA (proven loop): out trow = (m<<4)+Crow, A row = (m<<4)+l15+d
    f32x4 acc1[2][4];
    #pragma unroll
    for (int n = 0; n < 4; ++n){
        float bv = b1[(wave << 6) + (n << 4) + l15];
        acc1[0][n] = f32x4{bv, bv, bv, bv};
        acc1[1][n] = f32x4{bv, bv, bv, bv};
    }
    #pragma unroll
    for (int d = 0; d < 3; ++d){
        #pragma unroll
        for (int kt = 0; kt < 3; ++kt){
            short8 ah[2], al[2];
            #pragma unroll
            for (int m = 0; m < 2; ++m){
                int off = ((m << 4) + l15 + d)*XSTR + kt*32 + lg4*8;
                ah[m] = __builtin_bit_cast(short8, *(const uint4*)(xhi + off));
                al[m] = __builtin_bit_cast(short8, *(const uint4*)(xlo + off));
            }
            #pragma unroll
            for (int n = 0; n < 4; ++n){
                int co_n = (wave << 6) + (n << 4) + l15;
                int wo = ((((d*3 + kt)*4 + lg4) << 8) + co_n) << 3;
                short8 bh = __builtin_bit_cast(short8, *(const uint4*)(w1fhi + wo));
                short8 bl = __builtin_bit_cast(short8, *(const uint4*)(w1flo + wo));
                #pragma unroll
                for (int m = 0; m < 2; ++m){
                    acc1[m][n] = __builtin_amdgcn_mfma_f32_16x16x32_bf16(ah[m], bh, acc1[m][n], 0, 0, 0);
                    acc1[m][n] = __builtin_amdgcn_mfma_f32_16x16x32_bf16(ah[m], bl, acc1[m][n], 0, 0, 0);
                    acc1[m][n] = __builtin_amdgcn_mfma_f32_16x16x32_bf16(al[m], bh, acc1[m][n], 0, 0, 0);
                }
            }
        }
    }
    // writeback: all 32 rows valid (t0 = bx*32, 25*32 = 800)
    #pragma unroll
    for (int m = 0; m < 2; ++m){
        #pragma unroll
        for (int n = 0; n < 4; ++n){
            int co_n = (wave << 6) + (n << 4) + l15;
            #pragma unroll
            for (int j = 0; j < 4; ++j){
                int trow = (m << 4) + (lg4 << 2) + j;
                float v = fmaxf(acc1[m][n][j], 0.f);
                __hip_bfloat16 h = __float2bfloat16(v);
                __hip_bfloat16 l2 = __float2bfloat16(v - __bfloat162float(h));
                size_t idx = ((size_t)(b*T_LEN + t0 + trow) << 8) + co_n;
                ohi[idx] = h;
                olo[idx] = l2;
            }
        }
    }
}

// -------- conv2+conv3 via MFMA (grouped, co-half per block, 1 group per wave) --------
__global__ __launch_bounds__(256) void k_conv23(const __hip_bfloat16* __restrict__ hhi,
                                                const __hip_bfloat16* __restrict__ hlo,
                                                const __hip_bfloat16* __restrict__ w2fhi,
                                                const __hip_bfloat16* __restrict__ w2flo,
                                                const float* __restrict__ b2,
                                                const __hip_bfloat16* __restrict__ w3fhi,
                                                const __hip_bfloat16* __restrict__ w3flo,
                                                const float* __restrict__ b3,
                                                __hip_bfloat16* __restrict__ ohi,
                                                __hip_bfloat16* __restrict__ olo){
    __shared__ __align__(16) unsigned char inL[2][50*256];  // h1 planes rows t0-2..t0+47, 128 ci
    __shared__ __align__(16) unsigned char imL[2][34*256];  // conv2 out rows t0-1..t0+32
    const int t0 = blockIdx.x * 32;
    const int b  = blockIdx.y;
    const int coBase = blockIdx.z << 7;     // 0 or 128
    const int tid = threadIdx.x;
    const int gl = tid >> 6;                // wave = local group (0..3)
    const int l = tid & 63;
    const int l15 = l & 15, lg4 = l >> 4;
    const int g = (coBase >> 5) + gl;       // global group (0..7)

    // stage input planes (swizzled, conv4-style); mask outside [0,T) -> zero-pad
    for (int i = tid; i < 2*800; i += 256){
        int p = (i >= 800);
        int c = i - (p ? 800 : 0);
        int r = c >> 4, c16 = c & 15;       // r 0..49, c16 0..15 (8 bf16 each)
        int t = t0 - 2 + r;
        uint4 v = make_uint4(0u,0u,0u,0u);
        if (t >= 0 && t < T_LEN){
            const __hip_bfloat16* src = (p ? hlo : hhi) + (((size_t)(b*T_LEN + t)) << 8) + coBase + (c16 << 3);
            v = *(const uint4*)src;
        }
        int off = (r << 8) + (c16 << 4);
        off ^= (r & 7) << 4;
        *(uint4*)(&inL[p][off]) = v;
    }
    __syncthreads();

    // conv2 MFMA: out orow 0..33 (t = t0-1+orow); A row = (m<<4)+l15+d (<=49)
    {
        f32x4 acc2[3][2];
        #pragma unroll
        for (int n = 0; n < 2; ++n){
            float bv = b2[(g << 5) + (n << 4) + l15];
            acc2[0][n] = f32x4{bv, bv, bv, bv};
            acc2[1][n] = f32x4{bv, bv, bv, bv};
            acc2[2][n] = f32x4{bv, bv, bv, bv};
        }
        #pragma unroll
        for (int d = 0; d < 3; ++d){
            short8 ah[3], al[3];
            #pragma unroll
            for (int m = 0; m < 3; ++m){
                int rr = (m << 4) + l15 + d;
                int off = (rr << 8) + (gl << 6) + (lg4 << 4);
                off ^= (rr & 7) << 4;
                ah[m] = __builtin_bit_cast(short8, *(const uint4*)(&inL[0][off]));
                al[m] = __builtin_bit_cast(short8, *(const uint4*)(&inL[1][off]));
            }
            #pragma unroll
            for (int n = 0; n < 2; ++n){
                int wo = (((((g*2 + n)*3 + d)*4 + lg4) << 4) + l15) << 3;
                short8 bh = __builtin_bit_cast(short8, *(const uint4*)(w2fhi + wo));
                short8 bl = __builtin_bit_cast(short8, *(const uint4*)(w2flo + wo));
                #pragma unroll
                for (int m = 0; m < 3; ++m){
                    acc2[m][n] = __builtin_amdgcn_mfma_f32_16x16x32_bf16(ah[m], bh, acc2[m][n], 0, 0, 0);
                    acc2[m][n] = __builtin_amdgcn_mfma_f32_16x16x32_bf16(ah[m], bl, acc2[m][n], 0, 0, 0);
                    acc2[m][n] = __builtin_amdgcn_mfma_f32_16x16x32_bf16(al[m], bh, acc2[m][n], 0, 0, 0);
                }
            }
        }
        // writeback intermediate: relu, zero-mask t outside [0,T), split bf16, swizzled
        #pragma unroll
        for (int m = 0; m < 3; ++m){
            #pragma unroll
            for (int n = 0; n < 2; ++n){
                int cl2 = (gl << 5) + (n << 4) + l15;
                #pragma unroll
                for (int j = 0; j < 4; ++j){
                    int orow = (m << 4) + (lg4 << 2) + j;
                    if (orow < 34){
                        int t = t0 - 1 + orow;
                        float v = (t >= 0 && t < T_LEN) ? fmaxf(acc2[m][n][j], 0.f) : 0.f;
                        __hip_bfloat16 h = __float2bfloat16(v);
                        __hip_bfloat16 l2 = __float2bfloat16(v - __bfloat162float(h));
                        int off = (orow << 8) + (cl2 << 1);
                        off ^= (orow & 7) << 4;
                        *(__hip_bfloat16*)(&imL[0][off]) = h;
                        *(__hip_bfloat16*)(&imL[1][off]) = l2;
                    }
                }
            }
        }
    }
    __syncthreads();

    // conv3 MFMA: out orow3 0..31 (t = t0+orow3); A row = (m<<4)+l15+d (<=33)
    {
        f32x4 acc3[2][2];
        #pragma unroll
        for (int n = 0; n < 2; ++n){
            float bv = b3[(g << 5) + (n << 4) + l15];
            acc3[0][n] = f32x4{bv, bv, bv, bv};
            acc3[1][n] = f32x4{bv, bv, bv, bv};
        }
        #pragma unroll
        for (int d = 0; d < 3; ++d){
            short8 ah[2], al[2];
            #pragma unroll
            for (int m = 0; m < 2; ++m){
                int rr = (m << 4) + l15 + d;
                int off = (rr << 8) + (gl << 6) + (lg4 << 4);
                off ^= (rr & 7) << 4;
                ah[m] = __builtin_bit_cast(short8, *(const uint4*)(&imL[0][off]));
                al[m] = __builtin_bit_cast(short8, *(const uint4*)(&imL[1][off]));
            }
            #pragma unroll
            for (int n = 0; n < 2; ++n){
                int wo = (((((g*2 + n)*3 + d)*4 + lg4) << 4) + l15) << 3;
                short8 bh = __builtin_bit_cast(short8, *(const uint4*)(w3fhi + wo));
                short8 bl = __builtin_bit_cast(short8, *(const uint4*)(w3flo + wo));
                #pragma unroll
                for (int m = 0; m < 2; ++m){
                    acc3[m][n] = __builtin_amdgcn_mfma_f32_16x16x32_bf16(ah[m], bh, acc3[m][n], 0, 0, 0);
                    acc3[m][n] = __builtin_amdgcn_mfma_f32_16x16x32_bf16(ah[m], bl, acc3[m][n], 0, 0, 0);
                    acc3[m][n] = __builtin_amdgcn_mfma_f32_16x16x32_bf16(al[m], bh, acc3[m][n], 0, 0, 0);
                }
            }
        }
        // store h3 planes (all rows valid)
        #pragma unroll
        for (int m = 0; m < 2; ++m){
            #pragma unroll
            for (int n = 0; n < 2; ++n){
                int co = coBase + (gl << 5) + (n << 4) + l15;
                #pragma unroll
                for (int j = 0; j < 4; ++j){
                    int orow3 = (m << 4) + (lg4 << 2) + j;
                    float v = fmaxf(acc3[m][n][j], 0.f);
                    __hip_bfloat16 h = __float2bfloat16(v);
                    __hip_bfloat16 l2 = __float2bfloat16(v - __bfloat162float(h));
                    size_t idx = ((size_t)(b*T_LEN + t0 + orow3) << 8) + co;
                    ohi[idx] = h;
                    olo[idx] = l2;
                }
            }
        }
    }
}

// -------- conv4 via MFMA 16x16x32 bf16, split hi/lo (proven, unchanged) --------
__global__ __launch_bounds__(256) void k_conv4(const __hip_bfloat16* __restrict__ hhi,
                                               const __hip_bfloat16* __restrict__ hlo,
                                               const __hip_bfloat16* __restrict__ wfhi,
                                               const __hip_bfloat16* __restrict__ wflo,
                                               const float* __restrict__ bias,
                                               float* __restrict__ ccep){
    __shared__ __align__(16) unsigned char aLds[2][34*512];
    const int gx = blockIdx.x;              // 400 = 16 b * 25 t-tiles
    const int b  = gx / 25;
    const int t0 = (gx - b*25) * 32;
    const int coBase = blockIdx.y << 7;     // 0 or 128
    const int tid = threadIdx.x;
    const int wave = tid >> 6;
    const int l = tid & 63;
    const int l15 = l & 15, lg = l >> 4;

    for (int i = tid; i < 2*1088; i += 256){
        int p = (i >= 1088);
        int c = i - (p ? 1088 : 0);
        int r = c >> 5, c16 = c & 31;
        int t = t0 - 1 + r;
        uint4 v = make_uint4(0u,0u,0u,0u);
        if (t >= 0 && t < T_LEN){
            const __hip_bfloat16* src = (p ? hlo : hhi) + (((size_t)(b*T_LEN + t)) << 8) + (c16 << 3);
            v = *(const uint4*)src;
        }
        int off = (r << 9) + (c16 << 4);
        off ^= (r & 7) << 4;
        *(uint4*)(&aLds[p][off]) = v;
    }
    __syncthreads();

    const int co0 = coBase + (wave << 5);
    f32x4 acc[2][2];
    #pragma unroll
    for (int n = 0; n < 2; ++n){
        int co = co0 + (n << 4) + l15;
        float bq = 0.f;
        if (co < OUT_CH){
            float q = (co < 111) ? (float)(111 - co) : (float)(co - 110);
            bq = bias[co] / q;
        }
        acc[0][n] = f32x4{bq, bq, bq, bq};
        acc[1][n] = f32x4{bq, bq, bq, bq};
    }

    for (int kt = 0; kt < 24; ++kt){
        const int d   = kt >> 3;
        const int cib = (kt & 7) << 6;
        short8 ah[2], al[2];
        #pragma unroll
        for (int m = 0; m < 2; ++m){
            int r = l15 + d + (m << 4);
            int off = (r << 9) + cib + (lg << 4);
            off ^= (r & 7) << 4;
            ah[m] = __builtin_bit_cast(short8, *(const uint4*)(&aLds[0][off]));
            al[m] = __builtin_bit_cast(short8, *(const uint4*)(&aLds[1][off]));
        }
        #pragma unroll
        for (int n = 0; n < 2; ++n){
            int co = co0 + (n << 4) + l15;
            size_t woff = ((size_t)((kt << 2) + lg) << 8) + co;
            short8 bh = __builtin_bit_cast(short8, *(const uint4*)(wfhi + (woff << 3)));
            short8 bl = __builtin_bit_cast(short8, *(const uint4*)(wflo + (woff << 3)));
            #pragma unroll
            for (int m = 0; m < 2; ++m){
                acc[m][n] = __builtin_amdgcn_mfma_f32_16x16x32_bf16(ah[m], bh, acc[m][n], 0, 0, 0);
                acc[m][n] = __builtin_amdgcn_mfma_f32_16x16x32_bf16(ah[m], bl, acc[m][n], 0, 0, 0);
                acc[m][n] = __builtin_amdgcn_mfma_f32_16x16x32_bf16(al[m], bh, acc[m][n], 0, 0, 0);
            }
        }
    }

    #pragma unroll
    for (int m = 0; m < 2; ++m){
        #pragma unroll
        for (int n = 0; n < 2; ++n){
            int co = co0 + (n << 4) + l15;
            #pragma unroll
            for (int j = 0; j < 4; ++j){
                int t = t0 + (m << 4) + (lg << 2) + j;
                ccep[((size_t)(b*T_LEN + t) << 8) + co] = acc[m][n][j];
            }
        }
    }
}

// -------- radix-4 Stockham stage; w1 from 512-entry table, w2/w3 via cmul (proven) --------
template<int N4, int Ns, bool INV, bool SKIP3>
__device__ __forceinline__ void r4s(const float2* __restrict__ src,
                                    float2* __restrict__ dst,
                                    const float2* __restrict__ Wt,
                                    int j){
    const int jm = j & (Ns - 1);
    float2 v0 = src[PHI(j)];
    float2 v1 = src[PHI(j + N4)];
    float2 v2 = src[PHI(j + 2*N4)];
    float2 v3 = make_float2(0.f, 0.f);
    if (!SKIP3) v3 = src[PHI(j + 3*N4)];
    if (Ns > 1){
        const int e = jm * (256 / Ns);
        float2 w1 = Wt[PHI(e)];
        if (INV) w1.y = -w1.y;
        float2 w2 = cmul(w1, w1);
        float2 w3 = cmul(w2, w1);
        v1 = cmul(v1, w1);
        v2 = cmul(v2, w2);
        if (!SKIP3) v3 = cmul(v3, w3);
    }
    float2 t0 = make_float2(v0.x + v2.x, v0.y + v2.y);
    float2 t1 = make_float2(v0.x - v2.x, v0.y - v2.y);
    float2 t2, t3;
    if (SKIP3){ t2 = v1; t3 = v1; }
    else {
        t2 = make_float2(v1.x + v3.x, v1.y + v3.y);
        t3 = make_float2(v1.x - v3.x, v1.y - v3.y);
    }
    float2 o0 = make_float2(t0.x + t2.x, t0.y + t2.y);
    float2 o2 = make_float2(t0.x - t2.x, t0.y - t2.y);
    float2 o1, o3;
    if (!INV){
        o1 = make_float2(t1.x + t3.y, t1.y - t3.x);
        o3 = make_float2(t1.x - t3.y, t1.y + t3.x);
    } else {
        o1 = make_float2(t1.x - t3.y, t1.y + t3.x);
        o3 = make_float2(t1.x + t3.y, t1.y - t3.x);
    }
    const int base = ((j - jm) << 2) + jm;
    dst[PHI(base)]          = o0;
    dst[PHI(base + Ns)]     = o1;
    dst[PHI(base + 2*Ns)]   = o2;
    dst[PHI(base + 3*Ns)]   = o3;
}

// -------- per-(b,t): fused-load fwd FFT -> merged G/Z-pack -> inv FFT -> fused r2+window+store --------
__global__ __launch_bounds__(256) void k_filter(const float* __restrict__ ccep,
                                                const float* __restrict__ z,
                                                float* __restrict__ zw){
    __shared__ __align__(16) float2 A[1152];
    __shared__ __align__(16) float2 Bb[1152];
    __shared__ __align__(16) float2 Wt[576];   // W_1024^k, k<512, PHI-padded
    const int t = blockIdx.x;
    const int b = blockIdx.y;
    const int tid = threadIdx.x;
    const float PI2 = 6.283185307179586f;

    for (int j = tid; j < 512; j += 256){
        float s, c;
        __sincosf(-PI2 * (float)j * (1.0f/1024.0f), &s, &c);
        Wt[PHI(j)] = make_float2(c, s);
    }
    // fused load + forward stage-1 (Ns=1, SKIP3: p[768..1023]=0)
    {
        const float* crow = &ccep[(b*T_LEN + t)*CSTRIDE];
        auto gen = [&](int i)->float2 {
            float av = (i >= 401 && i < 623) ? crow[i - 401] : 0.f;
            float fv = 0.f;
            if (i < 512){
                int zi = t*HOPSZ + i - 255;
                fv = (zi >= 0 && zi < ZLEN) ? z[b*ZLEN + zi] : 0.f;
            }
            return make_float2(av, fv);
        };
        int j = tid;
        float2 v0 = gen(j);
        float2 v1 = gen(j + 256);
        float2 v2 = gen(j + 512);
        float2 t0 = make_float2(v0.x + v2.x, v0.y + v2.y);
        float2 t1 = make_float2(v0.x - v2.x, v0.y - v2.y);
        int base = PHI(4*j);   // 4j..4j+3 contiguous in PHI space
        Bb[base]     = make_float2(t0.x + v1.x, t0.y + v1.y);
        Bb[base + 1] = make_float2(t1.x + v1.y, t1.y - v1.x);
        Bb[base + 2] = make_float2(t0.x - v1.x, t0.y - v1.y);
        Bb[base + 3] = make_float2(t1.x - v1.y, t1.y + v1.x);
    }
    __syncthreads();

    r4s<256,4,  false,false>(Bb, A,  Wt, tid); __syncthreads();
    r4s<256,16, false,false>(A,  Bb, Wt, tid); __syncthreads();
    r4s<256,64, false,false>(Bb, A,  Wt, tid); __syncthreads();
    r4s<256,256,false,false>(A,  Bb, Wt, tid); __syncthreads();

    // merged: G[k],G[512-k] -> Z'[k],Z'[512-k] written to A
    {
        const float LOG2_10_DIV10 = 0.33219280948873623f;
        auto unpackG = [&](int i)->float2 {
            float2 P = Bb[PHI(i)];
            float2 Q = Bb[PHI((1024 - i) & 1023)];
            float Are = 0.5f * (P.x + Q.x);
            float Aim = 0.5f * (P.y - Q.y);
            float Fx  = 0.5f * (P.y + Q.y);
            float Fy  = 0.5f * (Q.x - P.x);
            float mag = exp2f(Are * LOG2_10_DIV10) * (1.0f/1024.0f);
            float s, c;
            __sincosf(Aim, &s, &c);
            float Hx = mag * c, Hy = mag * s;
            return make_float2(Fx*Hx + Fy*Hy, Fx*Hy - Fy*Hx);
        };
        int k = tid;
        float2 G  = unpackG(k);
        float2 G2 = unpackG(512 - k);
        float sx = G.x + G2.x, sy = G.y - G2.y;
        float dx = G.x - G2.x, dy = G.y + G2.y;
        float2 V = Wt[PHI(k)];
        float ux = dx*V.x + dy*V.y;
        float uy = dy*V.x - dx*V.y;
        A[PHI(k)] = make_float2(sx - uy, sy + ux);
        if (k){
            A[PHI(512 - k)] = make_float2(sx + uy, ux - sy);
        } else {
            float2 G3 = unpackG(256);
            A[PHI(256)] = make_float2(2.f*G3.x, -2.f*G3.y);
        }
    }
    __syncthreads();

    if (tid < 128) r4s<128,1, true,false>(A,  Bb, Wt, tid);
    __syncthreads();
    if (tid < 128) r4s<128,4, true,false>(Bb, A,  Wt, tid);
    __syncthreads();
    if (tid < 128) r4s<128,16,true,false>(A,  Bb, Wt, tid);
    __syncthreads();
    if (tid < 128) r4s<128,64,true,false>(Bb, A,  Wt, tid);
    __syncthreads();

    // fused final radix-2 + Hann + store; only z[0..255] is consumed (direct __cosf windows)
    {
        int j = tid;
        float2 u = A[PHI(j)];
        float2 v = A[PHI(j + 256)];
        float2 w = Wt[PHI(2*j)];
        w.y = -w.y;
        float2 vv = cmul(v, w);
        float zx = u.x + vv.x, zy = u.y + vv.y;   // z[j]
        int n1 = 511 - 2*j;    // odd  -> Re z[j]
        int n2 = 510 - 2*j;    // even -> Im z[j]
        float wv1 = 0.5f * (1.0f - __cosf(PI2 * (float)n1 * (1.0f/512.0f)));
        float wv2 = 0.5f * (1.0f - __cosf(PI2 * (float)n2 * (1.0f/512.0f)));
        float* zrow = &zw[(size_t)(b*T_LEN + t)*512];
        zrow[n1] = zx * wv1;
        zrow[n2] = zy * wv2;
    }
}

// -------- OLA + clip --------
__global__ __launch_bounds__(256) void k_ola(const float* __restrict__ zw,
                                             float* __restrict__ out){
    const int t = blockIdx.x;
    const int b = blockIdx.y;
    const int h = threadIdx.x;
    const int tm = (t + T_LEN - 1) % T_LEN;
    float v = zw[(size_t)(b*T_LEN + t)*512 + h]
            + zw[(size_t)(b*T_LEN + tm)*512 + 256 + h];
    v = fminf(fmaxf(v, -1.0f), 1.0f);
    out[(size_t)b*ZLEN + t*HOPSZ + h] = v;
}

extern "C" void kernel_launch(void* const* d_in, const int* in_sizes, int n_in,
                              void* d_out, int out_size, void* d_ws, size_t ws_size,
                              hipStream_t stream){
    const float* x  = (const float*)d_in[0];
    const float* z  = (const float*)d_in[1];
    const float* W1 = (const float*)d_in[2];
    const float* b1 = (const float*)d_in[3];
    const float* W2 = (const float*)d_in[4];
    const float* b2 = (const float*)d_in[5];
    const float* W3 = (const float*)d_in[6];
    const float* b3 = (const float*)d_in[7];
    const float* W4 = (const float*)d_in[8];
    const float* b4 = (const float*)d_in[9];
    float* out = (float*)d_out;
    float* ws  = (float*)d_ws;

    // layout (floats):
    // region A (3,276,800 fl): h1 planes (conv1m out) -> later overwritten by ccep (conv4 out)
    __hip_bfloat16* h1hi = (__hip_bfloat16*)ws;
    __hip_bfloat16* h1lo = h1hi + 3276800;
    float* ccep = ws;                                         // overlays h1 planes (dead by conv4)
    // region B: h3 planes (conv23 out)
    __hip_bfloat16* h3hi = (__hip_bfloat16*)(ws + 3276800);
    __hip_bfloat16* h3lo = h3hi + 3276800;
    float* zwb  = ws + 6553600;                               // 6,553,600 fl
    // weight tables in FRONT of zwb (read by convs, overwritten later by k_filter)
    __hip_bfloat16* w1fhi = (__hip_bfloat16*)zwb;             // 73728
    __hip_bfloat16* w1flo = w1fhi + 73728;
    __hip_bfloat16* w2fhi = w1flo + 73728;                    // 24576
    __hip_bfloat16* w2flo = w2fhi + 24576;
    __hip_bfloat16* w3fhi = w2flo + 24576;                    // 24576
    __hip_bfloat16* w3flo = w3fhi + 24576;
    __hip_bfloat16* wfhi  = w3flo + 24576;                    // 196608
    __hip_bfloat16* wflo  = wfhi + 196608;                    // ends @ 638,976 bf16

    dim3 blk(256);
    dim3 gwt(768, 4);
    dim3 gc1(25, B_SZ);               // t-tile 32
    dim3 gc23(25, B_SZ, 2);           // t-tile 32, co-half
    dim3 gc4(400, 2);
    dim3 gf(T_LEN, B_SZ);             // (800,16)

    k_wtrans<<<gwt, blk, 0, stream>>>(W1, W2, W3, W4, w1fhi, w1flo, w2fhi, w2flo,
                                      w3fhi, w3flo, wfhi, wflo);
    k_conv1m<<<gc1, blk, 0, stream>>>(x, w1fhi, w1flo, b1, h1hi, h1lo);
    k_conv23<<<gc23, blk, 0, stream>>>(h1hi, h1lo, w2fhi, w2flo, b2, w3fhi, w3flo, b3, h3hi, h3lo);
    k_conv4<<<gc4, blk, 0, stream>>>(h3hi, h3lo, wfhi, wflo, b4, ccep);
    k_filter<<<gf, blk, 0, stream>>>(ccep, z, zwb);
    k_ola<<<gf, blk, 0, stream>>>(zwb, out);
}